// Round 4
// baseline (394.746 us; speedup 1.0000x reference)
//
#include <hip/hip_runtime.h>

#define N_NODES 50000
#define N_EDGES 640000
#define D 128

#define SCAN_BLOCK 256
#define SCAN_NBLK ((N_NODES + SCAN_BLOCK - 1) / SCAN_BLOCK)  // 196

// ---------------------------------------------------------------------------
// Degree histogram: deg[dst]++ per edge (int atomics, one-time)
// ---------------------------------------------------------------------------
__global__ void deg_kernel(const int* __restrict__ dst, int* __restrict__ deg) {
    int e = blockIdx.x * blockDim.x + threadIdx.x;
    if (e < N_EDGES) atomicAdd(&deg[dst[e]], 1);
}

// ---------------------------------------------------------------------------
// Hierarchical scan, step 1: per-block sums of deg (196 blocks x 256)
// ---------------------------------------------------------------------------
__global__ __launch_bounds__(SCAN_BLOCK) void scan_partial(const int* __restrict__ deg,
                                                           int* __restrict__ partial) {
    __shared__ int sm[SCAN_BLOCK];
    const int t = threadIdx.x;
    const int i = blockIdx.x * SCAN_BLOCK + t;
    sm[t] = (i < N_NODES) ? deg[i] : 0;
    __syncthreads();
#pragma unroll
    for (int off = SCAN_BLOCK / 2; off > 0; off >>= 1) {
        if (t < off) sm[t] += sm[t + off];
        __syncthreads();
    }
    if (t == 0) partial[blockIdx.x] = sm[0];
}

// ---------------------------------------------------------------------------
// Step 2: single-block scan over the 196 partials -> exclusive block offsets.
// ---------------------------------------------------------------------------
__global__ __launch_bounds__(SCAN_BLOCK) void scan_offsets(const int* __restrict__ partial,
                                                           int* __restrict__ block_off,
                                                           int* __restrict__ row_off) {
    __shared__ int sm[SCAN_BLOCK];
    const int t = threadIdx.x;
    int v = (t < SCAN_NBLK) ? partial[t] : 0;
    sm[t] = v;
    __syncthreads();
    int x = v;
#pragma unroll
    for (int off = 1; off < SCAN_BLOCK; off <<= 1) {
        int y = (t >= off) ? sm[t - off] : 0;
        __syncthreads();
        x += y;
        sm[t] = x;
        __syncthreads();
    }
    if (t < SCAN_NBLK) block_off[t] = x - v;          // exclusive prefix
    if (t == SCAN_BLOCK - 1) row_off[N_NODES] = x;    // grand total
}

// ---------------------------------------------------------------------------
// Step 3: in-block exclusive scan + block offset -> row_off, cursor
// ---------------------------------------------------------------------------
__global__ __launch_bounds__(SCAN_BLOCK) void scan_final(const int* __restrict__ deg,
                                                         const int* __restrict__ block_off,
                                                         int* __restrict__ row_off,
                                                         int* __restrict__ cursor) {
    __shared__ int sm[SCAN_BLOCK];
    const int t = threadIdx.x;
    const int i = blockIdx.x * SCAN_BLOCK + t;
    int v = (i < N_NODES) ? deg[i] : 0;
    sm[t] = v;
    __syncthreads();
    int x = v;
#pragma unroll
    for (int off = 1; off < SCAN_BLOCK; off <<= 1) {
        int y = (t >= off) ? sm[t - off] : 0;
        __syncthreads();
        x += y;
        sm[t] = x;
        __syncthreads();
    }
    int excl = x - v + block_off[blockIdx.x];
    if (i < N_NODES) {
        row_off[i] = excl;
        cursor[i] = excl;
    }
}

// ---------------------------------------------------------------------------
// CSR fill: csr_src[cursor[dst[e]]++] = src[e] (int atomics, one-time)
// ---------------------------------------------------------------------------
__global__ void fill_csr(const int* __restrict__ src, const int* __restrict__ dst,
                         int* __restrict__ cursor, int* __restrict__ csr_src) {
    int e = blockIdx.x * blockDim.x + threadIdx.x;
    if (e < N_EDGES) {
        int pos = atomicAdd(&cursor[dst[e]], 1);
        csr_src[pos] = src[e];
    }
}

// ---------------------------------------------------------------------------
// Gather-aggregate: mean[node, :] = (1/max(deg,1)) * sum_k feat[csr_src[k], :]
// 32 lanes per node, float4 per lane. 2-way unroll for memory-level parallelism.
// ---------------------------------------------------------------------------
__global__ __launch_bounds__(256) void gather_kernel(const float* __restrict__ feat,
                                                     const int* __restrict__ row_off,
                                                     const int* __restrict__ csr_src,
                                                     float* __restrict__ mean) {
    int gid = blockIdx.x * blockDim.x + threadIdx.x;
    int node = gid >> 5;
    if (node >= N_NODES) return;
    int c = (gid & 31) * 4;
    int beg = row_off[node];
    int end = row_off[node + 1];

    float4 s0 = make_float4(0.f, 0.f, 0.f, 0.f);
    float4 s1 = make_float4(0.f, 0.f, 0.f, 0.f);
    int k = beg;
    for (; k + 2 <= end; k += 2) {
        int a0 = csr_src[k];
        int a1 = csr_src[k + 1];
        float4 v0 = *reinterpret_cast<const float4*>(&feat[(size_t)a0 * D + c]);
        float4 v1 = *reinterpret_cast<const float4*>(&feat[(size_t)a1 * D + c]);
        s0.x += v0.x; s0.y += v0.y; s0.z += v0.z; s0.w += v0.w;
        s1.x += v1.x; s1.y += v1.y; s1.z += v1.z; s1.w += v1.w;
    }
    if (k < end) {
        int a0 = csr_src[k];
        float4 v0 = *reinterpret_cast<const float4*>(&feat[(size_t)a0 * D + c]);
        s0.x += v0.x; s0.y += v0.y; s0.z += v0.z; s0.w += v0.w;
    }
    float inv = 1.0f / fmaxf((float)(end - beg), 1.0f);
    *reinterpret_cast<float4*>(&mean[(size_t)node * D + c]) =
        make_float4((s0.x + s1.x) * inv, (s0.y + s1.y) * inv,
                    (s0.z + s1.z) * inv, (s0.w + s1.w) * inv);
}

// ---------------------------------------------------------------------------
// Register-tiled fused SAGE dense step:
//   out = [relu]( mean @ Wl + bias + feat @ Wr )
// Viewed as [mean|feat] (k=0..255) @ [Wl;Wr]. Block: 256 thr, 32 rows x 128
// cols; thread tile 2 rows x 8 cols. A-tile in LDS [32][258] (pad 2 -> row
// groups land on banks {0,4,8,12}: conflict-free ds_read_b128). W from L1/L2.
// ---------------------------------------------------------------------------
template <bool RELU>
__global__ __launch_bounds__(256) void sage_gemm(
    const float* __restrict__ feat,   // [N, D] root features
    const float* __restrict__ mean,   // [N, D] neighbor means
    const float* __restrict__ Wl,     // [D, D] row-major [k][c]
    const float* __restrict__ bias,   // [D]
    const float* __restrict__ Wr,     // [D, D]
    float* __restrict__ out)          // [N, D]
{
    constexpr int BR = 32;    // rows per block
    constexpr int KP = 258;   // padded k-stride (floats)
    __shared__ float smA[BR][KP];
    const int t = threadIdx.x;
    const int row0 = blockIdx.x * BR;

    // Stage 32 rows: k 0..127 = mean, 128..255 = feat. 2048 float4 / 256 thr.
#pragma unroll
    for (int i = 0; i < 8; ++i) {
        int s = i * 256 + t;          // float4 slot
        int r = s >> 6;               // 64 float4 per row
        int kk = (s & 63) << 2;       // float offset 0..252
        int node = row0 + r;
        if (node >= N_NODES) node = N_NODES - 1;   // clamp (values unused)
        const float* srcp = (kk < 128) ? &mean[(size_t)node * D + kk]
                                       : &feat[(size_t)node * D + (kk - 128)];
        *reinterpret_cast<float4*>(&smA[r][kk]) =
            *reinterpret_cast<const float4*>(srcp);
    }
    __syncthreads();

    const int cg = (t & 15) * 8;      // column base (16 groups x 8)
    const int rg = (t >> 4) * 2;      // row base (16 groups x 2)

    float acc[2][8];
    {
        float4 b0 = *reinterpret_cast<const float4*>(&bias[cg]);
        float4 b1 = *reinterpret_cast<const float4*>(&bias[cg + 4]);
#pragma unroll
        for (int r = 0; r < 2; ++r) {
            acc[r][0] = b0.x; acc[r][1] = b0.y; acc[r][2] = b0.z; acc[r][3] = b0.w;
            acc[r][4] = b1.x; acc[r][5] = b1.y; acc[r][6] = b1.z; acc[r][7] = b1.w;
        }
    }

#pragma unroll
    for (int half = 0; half < 2; ++half) {
        const float* __restrict__ W = half ? Wr : Wl;
        const int ko = half * 128;
        for (int k0 = 0; k0 < 128; k0 += 4) {
            float wv[4][8];
#pragma unroll
            for (int kk = 0; kk < 4; ++kk) {
                float4 wa = *reinterpret_cast<const float4*>(&W[(k0 + kk) * D + cg]);
                float4 wb = *reinterpret_cast<const float4*>(&W[(k0 + kk) * D + cg + 4]);
                wv[kk][0] = wa.x; wv[kk][1] = wa.y; wv[kk][2] = wa.z; wv[kk][3] = wa.w;
                wv[kk][4] = wb.x; wv[kk][5] = wb.y; wv[kk][6] = wb.z; wv[kk][7] = wb.w;
            }
#pragma unroll
            for (int r = 0; r < 2; ++r) {
                float4 a = *reinterpret_cast<const float4*>(&smA[rg + r][ko + k0]);
#pragma unroll
                for (int c = 0; c < 8; ++c) {
                    acc[r][c] += a.x * wv[0][c] + a.y * wv[1][c]
                               + a.z * wv[2][c] + a.w * wv[3][c];
                }
            }
        }
    }

#pragma unroll
    for (int r = 0; r < 2; ++r) {
        int node = row0 + rg + r;
        if (node < N_NODES) {
            float4 o0, o1;
            o0.x = acc[r][0]; o0.y = acc[r][1]; o0.z = acc[r][2]; o0.w = acc[r][3];
            o1.x = acc[r][4]; o1.y = acc[r][5]; o1.z = acc[r][6]; o1.w = acc[r][7];
            if (RELU) {
                o0.x = fmaxf(o0.x, 0.f); o0.y = fmaxf(o0.y, 0.f);
                o0.z = fmaxf(o0.z, 0.f); o0.w = fmaxf(o0.w, 0.f);
                o1.x = fmaxf(o1.x, 0.f); o1.y = fmaxf(o1.y, 0.f);
                o1.z = fmaxf(o1.z, 0.f); o1.w = fmaxf(o1.w, 0.f);
            }
            *reinterpret_cast<float4*>(&out[(size_t)node * D + cg]) = o0;
            *reinterpret_cast<float4*>(&out[(size_t)node * D + cg + 4]) = o1;
        }
    }
}

// ---------------------------------------------------------------------------
extern "C" void kernel_launch(void* const* d_in, const int* in_sizes, int n_in,
                              void* d_out, int out_size, void* d_ws, size_t ws_size,
                              hipStream_t stream) {
    const float* x   = (const float*)d_in[0];
    const int*   ei  = (const int*)d_in[1];
    const float* W1l = (const float*)d_in[2];
    const float* b1  = (const float*)d_in[3];
    const float* W1r = (const float*)d_in[4];
    const float* W2l = (const float*)d_in[5];
    const float* b2  = (const float*)d_in[6];
    const float* W2r = (const float*)d_in[7];
    float* out = (float*)d_out;

    const int* src = ei;             // edge_index[0]
    const int* dst = ei + N_EDGES;   // edge_index[1]

    // Workspace layout
    int*   deg       = (int*)d_ws;                     // 51200 ints
    int*   row_off   = deg + 51200;                    // 51200 ints (N+1 used)
    int*   cursor    = row_off + 51200;                // 51200 ints
    int*   partial   = cursor + 51200;                 // 256 ints
    int*   block_off = partial + 256;                  // 256 ints
    int*   csr_src   = block_off + 256;                // 640000 ints
    float* mean      = (float*)(csr_src + N_EDGES);    // N*D floats
    float* h         = mean + (size_t)N_NODES * D;     // N*D floats

    // ---- one-time CSR build ----
    hipMemsetAsync(deg, 0, N_NODES * sizeof(int), stream);
    deg_kernel<<<(N_EDGES + 255) / 256, 256, 0, stream>>>(dst, deg);
    scan_partial<<<SCAN_NBLK, SCAN_BLOCK, 0, stream>>>(deg, partial);
    scan_offsets<<<1, SCAN_BLOCK, 0, stream>>>(partial, block_off, row_off);
    scan_final<<<SCAN_NBLK, SCAN_BLOCK, 0, stream>>>(deg, block_off, row_off, cursor);
    fill_csr<<<(N_EDGES + 255) / 256, 256, 0, stream>>>(src, dst, cursor, csr_src);

    const int gemm_grid = (N_NODES + 31) / 32;  // 1563

    // ---- layer 1 ----
    gather_kernel<<<(N_NODES * 32 + 255) / 256, 256, 0, stream>>>(x, row_off, csr_src, mean);
    sage_gemm<true><<<gemm_grid, 256, 0, stream>>>(x, mean, W1l, b1, W1r, h);

    // ---- layer 2 ----
    gather_kernel<<<(N_NODES * 32 + 255) / 256, 256, 0, stream>>>(h, row_off, csr_src, mean);
    sage_gemm<false><<<gemm_grid, 256, 0, stream>>>(h, mean, W2l, b2, W2r, out);
}

// Round 5
// 333.030 us; speedup vs baseline: 1.1853x; 1.1853x over previous
//
#include <hip/hip_runtime.h>

#define N_NODES 50000
#define N_EDGES 640000
#define D 128

#define SCAN_BLOCK 256
#define SCAN_NBLK ((N_NODES + SCAN_BLOCK - 1) / SCAN_BLOCK)  // 196

// ---------------------------------------------------------------------------
// Degree histogram: deg[dst]++ per edge (int atomics, one-time)
// ---------------------------------------------------------------------------
__global__ void deg_kernel(const int* __restrict__ dst, int* __restrict__ deg) {
    int e = blockIdx.x * blockDim.x + threadIdx.x;
    if (e < N_EDGES) atomicAdd(&deg[dst[e]], 1);
}

// ---------------------------------------------------------------------------
// Hierarchical scan, step 1: per-block sums of deg (196 blocks x 256)
// ---------------------------------------------------------------------------
__global__ __launch_bounds__(SCAN_BLOCK) void scan_partial(const int* __restrict__ deg,
                                                           int* __restrict__ partial) {
    __shared__ int sm[SCAN_BLOCK];
    const int t = threadIdx.x;
    const int i = blockIdx.x * SCAN_BLOCK + t;
    sm[t] = (i < N_NODES) ? deg[i] : 0;
    __syncthreads();
#pragma unroll
    for (int off = SCAN_BLOCK / 2; off > 0; off >>= 1) {
        if (t < off) sm[t] += sm[t + off];
        __syncthreads();
    }
    if (t == 0) partial[blockIdx.x] = sm[0];
}

// ---------------------------------------------------------------------------
// Step 2: single-block scan over the 196 partials -> exclusive block offsets.
// ---------------------------------------------------------------------------
__global__ __launch_bounds__(SCAN_BLOCK) void scan_offsets(const int* __restrict__ partial,
                                                           int* __restrict__ block_off,
                                                           int* __restrict__ row_off) {
    __shared__ int sm[SCAN_BLOCK];
    const int t = threadIdx.x;
    int v = (t < SCAN_NBLK) ? partial[t] : 0;
    sm[t] = v;
    __syncthreads();
    int x = v;
#pragma unroll
    for (int off = 1; off < SCAN_BLOCK; off <<= 1) {
        int y = (t >= off) ? sm[t - off] : 0;
        __syncthreads();
        x += y;
        sm[t] = x;
        __syncthreads();
    }
    if (t < SCAN_NBLK) block_off[t] = x - v;          // exclusive prefix
    if (t == SCAN_BLOCK - 1) row_off[N_NODES] = x;    // grand total
}

// ---------------------------------------------------------------------------
// Step 3: in-block exclusive scan + block offset -> row_off, cursor
// ---------------------------------------------------------------------------
__global__ __launch_bounds__(SCAN_BLOCK) void scan_final(const int* __restrict__ deg,
                                                         const int* __restrict__ block_off,
                                                         int* __restrict__ row_off,
                                                         int* __restrict__ cursor) {
    __shared__ int sm[SCAN_BLOCK];
    const int t = threadIdx.x;
    const int i = blockIdx.x * SCAN_BLOCK + t;
    int v = (i < N_NODES) ? deg[i] : 0;
    sm[t] = v;
    __syncthreads();
    int x = v;
#pragma unroll
    for (int off = 1; off < SCAN_BLOCK; off <<= 1) {
        int y = (t >= off) ? sm[t - off] : 0;
        __syncthreads();
        x += y;
        sm[t] = x;
        __syncthreads();
    }
    int excl = x - v + block_off[blockIdx.x];
    if (i < N_NODES) {
        row_off[i] = excl;
        cursor[i] = excl;
    }
}

// ---------------------------------------------------------------------------
// CSR fill: csr_src[cursor[dst[e]]++] = src[e] (int atomics, one-time)
// ---------------------------------------------------------------------------
__global__ void fill_csr(const int* __restrict__ src, const int* __restrict__ dst,
                         int* __restrict__ cursor, int* __restrict__ csr_src) {
    int e = blockIdx.x * blockDim.x + threadIdx.x;
    if (e < N_EDGES) {
        int pos = atomicAdd(&cursor[dst[e]], 1);
        csr_src[pos] = src[e];
    }
}

// ---------------------------------------------------------------------------
// Gather-aggregate: mean[node, :] = (1/max(deg,1)) * sum_k feat[csr_src[k], :]
// 32 lanes per node, float4 per lane. 2-way unroll for memory-level parallelism.
// ---------------------------------------------------------------------------
__global__ __launch_bounds__(256) void gather_kernel(const float* __restrict__ feat,
                                                     const int* __restrict__ row_off,
                                                     const int* __restrict__ csr_src,
                                                     float* __restrict__ mean) {
    int gid = blockIdx.x * blockDim.x + threadIdx.x;
    int node = gid >> 5;
    if (node >= N_NODES) return;
    int c = (gid & 31) * 4;
    int beg = row_off[node];
    int end = row_off[node + 1];

    float4 s0 = make_float4(0.f, 0.f, 0.f, 0.f);
    float4 s1 = make_float4(0.f, 0.f, 0.f, 0.f);
    int k = beg;
    for (; k + 2 <= end; k += 2) {
        int a0 = csr_src[k];
        int a1 = csr_src[k + 1];
        float4 v0 = *reinterpret_cast<const float4*>(&feat[(size_t)a0 * D + c]);
        float4 v1 = *reinterpret_cast<const float4*>(&feat[(size_t)a1 * D + c]);
        s0.x += v0.x; s0.y += v0.y; s0.z += v0.z; s0.w += v0.w;
        s1.x += v1.x; s1.y += v1.y; s1.z += v1.z; s1.w += v1.w;
    }
    if (k < end) {
        int a0 = csr_src[k];
        float4 v0 = *reinterpret_cast<const float4*>(&feat[(size_t)a0 * D + c]);
        s0.x += v0.x; s0.y += v0.y; s0.z += v0.z; s0.w += v0.w;
    }
    float inv = 1.0f / fmaxf((float)(end - beg), 1.0f);
    *reinterpret_cast<float4*>(&mean[(size_t)node * D + c]) =
        make_float4((s0.x + s1.x) * inv, (s0.y + s1.y) * inv,
                    (s0.z + s1.z) * inv, (s0.w + s1.w) * inv);
}

// ---------------------------------------------------------------------------
// Two-tile LDS GEMM: out = [relu]( [mean|feat] @ [Wl;Wr] + bias )
// Block: 256 thr, 128 rows x 128 cols; thread tile 8x8 (split 4+4 rows/cols).
// K chunks of 16; A transposed [k][row] and W [k][col] both staged in LDS
// (double-buffered, reg-prefetch, 1 barrier/chunk). 4 ds_read_b128 -> 64 FMA.
// ---------------------------------------------------------------------------
template <bool RELU>
__global__ __launch_bounds__(256) void sage_gemm(
    const float* __restrict__ feat,   // [N, D] root features
    const float* __restrict__ mean,   // [N, D] neighbor means
    const float* __restrict__ Wl,     // [D, D] row-major [k][c]
    const float* __restrict__ bias,   // [D]
    const float* __restrict__ Wr,     // [D, D]
    float* __restrict__ out)          // [N, D]
{
    constexpr int BM = 128;
    constexpr int KC = 16;
    constexpr int KP = 132;   // padded stride (floats)
    __shared__ float At[2][KC][KP];   // A transposed: [k][row]
    __shared__ float Ws[2][KC][KP];   // W: [k][col]
    const int t = threadIdx.x;
    const int row0 = blockIdx.x * BM;
    const int rg = t >> 4;    // 0..15
    const int cg = t & 15;    // 0..15

    // A staging: slot s in [0,512): r = s&127, kq = s>>7 (float4 kq*4..+3)
    // W staging: slot s in [0,512): krow = s>>5, c4 = (s&31)*4
    float4 pa0, pa1, pw0, pw1;

    auto loadA = [&](int kc, int s) -> float4 {
        int r = s & 127;
        int kq = s >> 7;
        int kg = kc * KC + kq * 4;
        int node = row0 + r;
        if (node >= N_NODES) node = N_NODES - 1;   // clamp; values unused
        const float* p = (kg < 128) ? &mean[(size_t)node * D + kg]
                                    : &feat[(size_t)node * D + (kg - 128)];
        return *reinterpret_cast<const float4*>(p);
    };
    auto loadW = [&](int kc, int s) -> float4 {
        int krow = s >> 5;
        int c4 = (s & 31) << 2;
        int kg = kc * KC + krow;
        const float* p = (kg < 128) ? &Wl[(size_t)kg * D + c4]
                                    : &Wr[(size_t)(kg - 128) * D + c4];
        return *reinterpret_cast<const float4*>(p);
    };

    float acc[2][2][4][4] = {};   // [ri][ci][i][j], all static indexing

    // prologue: stage chunk 0 into buffer 0
    pa0 = loadA(0, t); pa1 = loadA(0, t + 256);
    pw0 = loadW(0, t); pw1 = loadW(0, t + 256);
    {
        int r = t & 127, kq = t >> 7;
        At[0][kq*4+0][r] = pa0.x; At[0][kq*4+1][r] = pa0.y;
        At[0][kq*4+2][r] = pa0.z; At[0][kq*4+3][r] = pa0.w;
        int s1i = t + 256; int r1 = s1i & 127, kq1 = s1i >> 7;
        At[0][kq1*4+0][r1] = pa1.x; At[0][kq1*4+1][r1] = pa1.y;
        At[0][kq1*4+2][r1] = pa1.z; At[0][kq1*4+3][r1] = pa1.w;
        int krow = t >> 5, c4 = (t & 31) << 2;
        *reinterpret_cast<float4*>(&Ws[0][krow][c4]) = pw0;
        int krow1 = s1i >> 5, c41 = (s1i & 31) << 2;
        *reinterpret_cast<float4*>(&Ws[0][krow1][c41]) = pw1;
    }
    __syncthreads();

    int cur = 0;
    for (int kc = 0; kc < 16; ++kc) {
        if (kc < 15) {   // issue next chunk's global loads (latency hidden by compute)
            pa0 = loadA(kc + 1, t); pa1 = loadA(kc + 1, t + 256);
            pw0 = loadW(kc + 1, t); pw1 = loadW(kc + 1, t + 256);
        }
#pragma unroll
        for (int k = 0; k < KC; ++k) {
            float4 a0 = *reinterpret_cast<const float4*>(&At[cur][k][rg * 4]);
            float4 a1 = *reinterpret_cast<const float4*>(&At[cur][k][64 + rg * 4]);
            float4 w0 = *reinterpret_cast<const float4*>(&Ws[cur][k][cg * 4]);
            float4 w1 = *reinterpret_cast<const float4*>(&Ws[cur][k][64 + cg * 4]);
            float av[2][4] = {{a0.x, a0.y, a0.z, a0.w}, {a1.x, a1.y, a1.z, a1.w}};
            float wv[2][4] = {{w0.x, w0.y, w0.z, w0.w}, {w1.x, w1.y, w1.z, w1.w}};
#pragma unroll
            for (int ri = 0; ri < 2; ++ri)
#pragma unroll
            for (int i = 0; i < 4; ++i)
#pragma unroll
            for (int ci = 0; ci < 2; ++ci)
#pragma unroll
            for (int j = 0; j < 4; ++j)
                acc[ri][ci][i][j] += av[ri][i] * wv[ci][j];
        }
        if (kc < 15) {   // write next chunk into the other buffer
            int nxt = cur ^ 1;
            int r = t & 127, kq = t >> 7;
            At[nxt][kq*4+0][r] = pa0.x; At[nxt][kq*4+1][r] = pa0.y;
            At[nxt][kq*4+2][r] = pa0.z; At[nxt][kq*4+3][r] = pa0.w;
            int s1i = t + 256; int r1 = s1i & 127, kq1 = s1i >> 7;
            At[nxt][kq1*4+0][r1] = pa1.x; At[nxt][kq1*4+1][r1] = pa1.y;
            At[nxt][kq1*4+2][r1] = pa1.z; At[nxt][kq1*4+3][r1] = pa1.w;
            int krow = t >> 5, c4 = (t & 31) << 2;
            *reinterpret_cast<float4*>(&Ws[nxt][krow][c4]) = pw0;
            int krow1 = s1i >> 5, c41 = (s1i & 31) << 2;
            *reinterpret_cast<float4*>(&Ws[nxt][krow1][c41]) = pw1;
            __syncthreads();
            cur = nxt;
        }
    }

    // epilogue: add bias, relu, store (rows rg*4+i and 64+rg*4+i; cols same split)
    float4 b0 = *reinterpret_cast<const float4*>(&bias[cg * 4]);
    float4 b1 = *reinterpret_cast<const float4*>(&bias[64 + cg * 4]);
    float bv[2][4] = {{b0.x, b0.y, b0.z, b0.w}, {b1.x, b1.y, b1.z, b1.w}};
#pragma unroll
    for (int ri = 0; ri < 2; ++ri)
#pragma unroll
    for (int i = 0; i < 4; ++i) {
        int node = row0 + ri * 64 + rg * 4 + i;
        if (node < N_NODES) {
#pragma unroll
            for (int ci = 0; ci < 2; ++ci) {
                float4 o;
                o.x = acc[ri][ci][i][0] + bv[ci][0];
                o.y = acc[ri][ci][i][1] + bv[ci][1];
                o.z = acc[ri][ci][i][2] + bv[ci][2];
                o.w = acc[ri][ci][i][3] + bv[ci][3];
                if (RELU) {
                    o.x = fmaxf(o.x, 0.f); o.y = fmaxf(o.y, 0.f);
                    o.z = fmaxf(o.z, 0.f); o.w = fmaxf(o.w, 0.f);
                }
                *reinterpret_cast<float4*>(&out[(size_t)node * D + ci * 64 + cg * 4]) = o;
            }
        }
    }
}

// ---------------------------------------------------------------------------
extern "C" void kernel_launch(void* const* d_in, const int* in_sizes, int n_in,
                              void* d_out, int out_size, void* d_ws, size_t ws_size,
                              hipStream_t stream) {
    const float* x   = (const float*)d_in[0];
    const int*   ei  = (const int*)d_in[1];
    const float* W1l = (const float*)d_in[2];
    const float* b1  = (const float*)d_in[3];
    const float* W1r = (const float*)d_in[4];
    const float* W2l = (const float*)d_in[5];
    const float* b2  = (const float*)d_in[6];
    const float* W2r = (const float*)d_in[7];
    float* out = (float*)d_out;

    const int* src = ei;             // edge_index[0]
    const int* dst = ei + N_EDGES;   // edge_index[1]

    // Workspace layout
    int*   deg       = (int*)d_ws;                     // 51200 ints
    int*   row_off   = deg + 51200;                    // 51200 ints (N+1 used)
    int*   cursor    = row_off + 51200;                // 51200 ints
    int*   partial   = cursor + 51200;                 // 256 ints
    int*   block_off = partial + 256;                  // 256 ints
    int*   csr_src   = block_off + 256;                // 640000 ints
    float* mean      = (float*)(csr_src + N_EDGES);    // N*D floats
    float* h         = mean + (size_t)N_NODES * D;     // N*D floats

    // ---- one-time CSR build ----
    hipMemsetAsync(deg, 0, N_NODES * sizeof(int), stream);
    deg_kernel<<<(N_EDGES + 255) / 256, 256, 0, stream>>>(dst, deg);
    scan_partial<<<SCAN_NBLK, SCAN_BLOCK, 0, stream>>>(deg, partial);
    scan_offsets<<<1, SCAN_BLOCK, 0, stream>>>(partial, block_off, row_off);
    scan_final<<<SCAN_NBLK, SCAN_BLOCK, 0, stream>>>(deg, block_off, row_off, cursor);
    fill_csr<<<(N_EDGES + 255) / 256, 256, 0, stream>>>(src, dst, cursor, csr_src);

    const int gemm_grid = (N_NODES + 127) / 128;  // 391

    // ---- layer 1 ----
    gather_kernel<<<(N_NODES * 32 + 255) / 256, 256, 0, stream>>>(x, row_off, csr_src, mean);
    sage_gemm<true><<<gemm_grid, 256, 0, stream>>>(x, mean, W1l, b1, W1r, h);

    // ---- layer 2 ----
    gather_kernel<<<(N_NODES * 32 + 255) / 256, 256, 0, stream>>>(h, row_off, csr_src, mean);
    sage_gemm<false><<<gemm_grid, 256, 0, stream>>>(h, mean, W2l, b2, W2r, out);
}

// Round 6
// 225.420 us; speedup vs baseline: 1.7512x; 1.4774x over previous
//
#include <hip/hip_runtime.h>

#define N_NODES 50000
#define N_EDGES 640000
#define D 128

#define SCAN_BLOCK 256
#define SCAN_NBLK ((N_NODES + SCAN_BLOCK - 1) / SCAN_BLOCK)  // 196

typedef __attribute__((ext_vector_type(8))) short bf16x8;   // 8 bf16 (4 VGPRs)
typedef __attribute__((ext_vector_type(4))) float f32x4;

__device__ __forceinline__ unsigned short f2bf(float f) {
    union { float f; unsigned u; } v; v.f = f;
    unsigned u = v.u;
    unsigned r = u + 0x7FFFu + ((u >> 16) & 1u);   // RNE
    return (unsigned short)(r >> 16);
}
__device__ __forceinline__ float bf2f(unsigned short s) {
    union { unsigned u; float f; } v; v.u = ((unsigned)s) << 16; return v.f;
}

// ---------------------------------------------------------------------------
// Degree histogram: deg[dst]++ per edge (int atomics, one-time)
// ---------------------------------------------------------------------------
__global__ void deg_kernel(const int* __restrict__ dst, int* __restrict__ deg) {
    int e = blockIdx.x * blockDim.x + threadIdx.x;
    if (e < N_EDGES) atomicAdd(&deg[dst[e]], 1);
}

// ---------------------------------------------------------------------------
// Hierarchical scan (3 kernels)
// ---------------------------------------------------------------------------
__global__ __launch_bounds__(SCAN_BLOCK) void scan_partial(const int* __restrict__ deg,
                                                           int* __restrict__ partial) {
    __shared__ int sm[SCAN_BLOCK];
    const int t = threadIdx.x;
    const int i = blockIdx.x * SCAN_BLOCK + t;
    sm[t] = (i < N_NODES) ? deg[i] : 0;
    __syncthreads();
#pragma unroll
    for (int off = SCAN_BLOCK / 2; off > 0; off >>= 1) {
        if (t < off) sm[t] += sm[t + off];
        __syncthreads();
    }
    if (t == 0) partial[blockIdx.x] = sm[0];
}

__global__ __launch_bounds__(SCAN_BLOCK) void scan_offsets(const int* __restrict__ partial,
                                                           int* __restrict__ block_off,
                                                           int* __restrict__ row_off) {
    __shared__ int sm[SCAN_BLOCK];
    const int t = threadIdx.x;
    int v = (t < SCAN_NBLK) ? partial[t] : 0;
    sm[t] = v;
    __syncthreads();
    int x = v;
#pragma unroll
    for (int off = 1; off < SCAN_BLOCK; off <<= 1) {
        int y = (t >= off) ? sm[t - off] : 0;
        __syncthreads();
        x += y;
        sm[t] = x;
        __syncthreads();
    }
    if (t < SCAN_NBLK) block_off[t] = x - v;
    if (t == SCAN_BLOCK - 1) row_off[N_NODES] = x;
}

__global__ __launch_bounds__(SCAN_BLOCK) void scan_final(const int* __restrict__ deg,
                                                         const int* __restrict__ block_off,
                                                         int* __restrict__ row_off,
                                                         int* __restrict__ cursor) {
    __shared__ int sm[SCAN_BLOCK];
    const int t = threadIdx.x;
    const int i = blockIdx.x * SCAN_BLOCK + t;
    int v = (i < N_NODES) ? deg[i] : 0;
    sm[t] = v;
    __syncthreads();
    int x = v;
#pragma unroll
    for (int off = 1; off < SCAN_BLOCK; off <<= 1) {
        int y = (t >= off) ? sm[t - off] : 0;
        __syncthreads();
        x += y;
        sm[t] = x;
        __syncthreads();
    }
    int excl = x - v + block_off[blockIdx.x];
    if (i < N_NODES) {
        row_off[i] = excl;
        cursor[i] = excl;
    }
}

// ---------------------------------------------------------------------------
// CSR fill: csr_src[cursor[dst[e]]++] = src[e]
// ---------------------------------------------------------------------------
__global__ void fill_csr(const int* __restrict__ src, const int* __restrict__ dst,
                         int* __restrict__ cursor, int* __restrict__ csr_src) {
    int e = blockIdx.x * blockDim.x + threadIdx.x;
    if (e < N_EDGES) {
        int pos = atomicAdd(&cursor[dst[e]], 1);
        csr_src[pos] = src[e];
    }
}

// ---------------------------------------------------------------------------
// fp32 -> bf16 elementwise (8 per thread)
// ---------------------------------------------------------------------------
__global__ void cvt_f32_bf16(const float* __restrict__ in,
                             unsigned short* __restrict__ outp, int n8) {
    int i = blockIdx.x * blockDim.x + threadIdx.x;
    if (i >= n8) return;
    float4 a = *reinterpret_cast<const float4*>(&in[(size_t)i * 8]);
    float4 b = *reinterpret_cast<const float4*>(&in[(size_t)i * 8 + 4]);
    bf16x8 o;
    o[0] = (short)f2bf(a.x); o[1] = (short)f2bf(a.y);
    o[2] = (short)f2bf(a.z); o[3] = (short)f2bf(a.w);
    o[4] = (short)f2bf(b.x); o[5] = (short)f2bf(b.y);
    o[6] = (short)f2bf(b.z); o[7] = (short)f2bf(b.w);
    *reinterpret_cast<bf16x8*>(&outp[(size_t)i * 8]) = o;
}

// ---------------------------------------------------------------------------
// Build Wt[col][k] bf16 from Wl[k][c], Wr[k][c] (k stacked to 256)
// ---------------------------------------------------------------------------
__global__ void build_wt(const float* __restrict__ Wl, const float* __restrict__ Wr,
                         unsigned short* __restrict__ Wt) {
    int i = blockIdx.x * blockDim.x + threadIdx.x;   // 128*256
    if (i >= 128 * 256) return;
    int c = i >> 8, k = i & 255;
    float v = (k < 128) ? Wl[k * 128 + c] : Wr[(k - 128) * 128 + c];
    Wt[c * 256 + k] = f2bf(v);
}

// ---------------------------------------------------------------------------
// Gather-aggregate (bf16 in/out, fp32 accumulate): one wave per node.
// Lane layout: grp = l>>4 walks neighbors (4 at a time), (l&15)*8 = col slice.
// ---------------------------------------------------------------------------
__global__ __launch_bounds__(256) void gather_bf16(const unsigned short* __restrict__ feat,
                                                   const int* __restrict__ row_off,
                                                   const int* __restrict__ csr_src,
                                                   unsigned short* __restrict__ mean) {
    int node = (blockIdx.x * 256 + threadIdx.x) >> 6;   // wave-uniform
    int l = threadIdx.x & 63;
    int grp = l >> 4;
    int c8 = (l & 15) * 8;
    int beg = row_off[node];
    int end = row_off[node + 1];

    float s[8] = {0.f, 0.f, 0.f, 0.f, 0.f, 0.f, 0.f, 0.f};
    for (int k = beg + grp; k < end; k += 4) {
        int srcn = csr_src[k];
        bf16x8 v = *reinterpret_cast<const bf16x8*>(&feat[(size_t)srcn * D + c8]);
#pragma unroll
        for (int j = 0; j < 8; ++j) s[j] += bf2f((unsigned short)v[j]);
    }
#pragma unroll
    for (int j = 0; j < 8; ++j) {
        s[j] += __shfl_xor(s[j], 16, 64);
        s[j] += __shfl_xor(s[j], 32, 64);
    }
    if (grp == 0) {
        float inv = 1.0f / fmaxf((float)(end - beg), 1.0f);
        bf16x8 o;
#pragma unroll
        for (int j = 0; j < 8; ++j) o[j] = (short)f2bf(s[j] * inv);
        *reinterpret_cast<bf16x8*>(&mean[(size_t)node * D + c8]) = o;
    }
}

// ---------------------------------------------------------------------------
// MFMA GEMM: out = [relu]( [mean|root] @ [Wl;Wr] + bias ), K=256, bf16 inputs.
// 4 waves/block, BM=64; wave = 16 rows x 128 cols = 8 accum frags, 64 MFMAs.
// A-frag: row=l&15, k=(l>>4)*8+j. B-frag from Wt[col][k]: col=l&15.
// C/D: col=l&15, row=(l>>4)*4+reg (verified layout).
// No LDS: Wt (64KB) is L1/L2-resident; A rows read once.
// ---------------------------------------------------------------------------
template <bool RELU, bool OUTBF16>
__global__ __launch_bounds__(256) void sage_gemm_mfma(
    const unsigned short* __restrict__ Amean,   // [N,128] bf16
    const unsigned short* __restrict__ Aroot,   // [N,128] bf16
    const unsigned short* __restrict__ Wt,      // [128 cols][256 k] bf16
    const float* __restrict__ bias,             // [128] fp32
    float* __restrict__ outf,                   // fp32 out (if !OUTBF16)
    unsigned short* __restrict__ outb)          // bf16 out (if OUTBF16)
{
    const int t = threadIdx.x;
    const int w = t >> 6;
    const int l = t & 63;
    const int row0 = blockIdx.x * 64 + w * 16;

    int arow = row0 + (l & 15);
    if (arow >= N_NODES) arow = N_NODES - 1;    // clamp; C-write guarded
    const int k8 = (l >> 4) * 8;

    f32x4 acc[8] = {};

#pragma unroll
    for (int kc = 0; kc < 8; ++kc) {
        const unsigned short* ap = (kc < 4)
            ? &Amean[(size_t)arow * D + kc * 32 + k8]
            : &Aroot[(size_t)arow * D + (kc - 4) * 32 + k8];
        bf16x8 af = *reinterpret_cast<const bf16x8*>(ap);
#pragma unroll
        for (int c = 0; c < 8; ++c) {
            bf16x8 bf = *reinterpret_cast<const bf16x8*>(
                &Wt[(size_t)(c * 16 + (l & 15)) * 256 + kc * 32 + k8]);
            acc[c] = __builtin_amdgcn_mfma_f32_16x16x32_bf16(af, bf, acc[c], 0, 0, 0);
        }
    }

    const int rbase = row0 + (l >> 4) * 4;
#pragma unroll
    for (int c = 0; c < 8; ++c) {
        const int col = c * 16 + (l & 15);
        const float b = bias[col];
#pragma unroll
        for (int i = 0; i < 4; ++i) {
            int r = rbase + i;
            if (r < N_NODES) {
                float v = acc[c][i] + b;
                if (RELU) v = fmaxf(v, 0.f);
                if (OUTBF16) outb[(size_t)r * D + col] = f2bf(v);
                else         outf[(size_t)r * D + col] = v;
            }
        }
    }
}

// ---------------------------------------------------------------------------
extern "C" void kernel_launch(void* const* d_in, const int* in_sizes, int n_in,
                              void* d_out, int out_size, void* d_ws, size_t ws_size,
                              hipStream_t stream) {
    const float* x   = (const float*)d_in[0];
    const int*   ei  = (const int*)d_in[1];
    const float* W1l = (const float*)d_in[2];
    const float* b1  = (const float*)d_in[3];
    const float* W1r = (const float*)d_in[4];
    const float* W2l = (const float*)d_in[5];
    const float* b2  = (const float*)d_in[6];
    const float* W2r = (const float*)d_in[7];
    float* out = (float*)d_out;

    const int* src = ei;             // edge_index[0]
    const int* dst = ei + N_EDGES;   // edge_index[1]

    // Workspace layout (ints first, then bf16 arrays; all 16B aligned)
    int* deg       = (int*)d_ws;                     // 51200
    int* row_off   = deg + 51200;                    // 51200 (N+1 used)
    int* cursor    = row_off + 51200;                // 51200
    int* partial   = cursor + 51200;                 // 256
    int* block_off = partial + 256;                  // 256
    int* csr_src   = block_off + 256;                // 640000
    unsigned short* x_bf    = (unsigned short*)(csr_src + N_EDGES);  // N*D
    unsigned short* h_bf    = x_bf + (size_t)N_NODES * D;            // N*D
    unsigned short* mean_bf = h_bf + (size_t)N_NODES * D;            // N*D
    unsigned short* Wt1     = mean_bf + (size_t)N_NODES * D;         // 128*256
    unsigned short* Wt2     = Wt1 + 128 * 256;                       // 128*256

    // ---- one-time CSR build + conversions ----
    hipMemsetAsync(deg, 0, N_NODES * sizeof(int), stream);
    deg_kernel<<<(N_EDGES + 255) / 256, 256, 0, stream>>>(dst, deg);
    scan_partial<<<SCAN_NBLK, SCAN_BLOCK, 0, stream>>>(deg, partial);
    scan_offsets<<<1, SCAN_BLOCK, 0, stream>>>(partial, block_off, row_off);
    scan_final<<<SCAN_NBLK, SCAN_BLOCK, 0, stream>>>(deg, block_off, row_off, cursor);
    fill_csr<<<(N_EDGES + 255) / 256, 256, 0, stream>>>(src, dst, cursor, csr_src);

    cvt_f32_bf16<<<(N_NODES * D / 8 + 255) / 256, 256, 0, stream>>>(x, x_bf, N_NODES * D / 8);
    build_wt<<<128, 256, 0, stream>>>(W1l, W1r, Wt1);
    build_wt<<<128, 256, 0, stream>>>(W2l, W2r, Wt2);

    const int gather_grid = N_NODES * 64 / 256;     // 12500
    const int gemm_grid = (N_NODES + 63) / 64;      // 782

    // ---- layer 1 ----
    gather_bf16<<<gather_grid, 256, 0, stream>>>(x_bf, row_off, csr_src, mean_bf);
    sage_gemm_mfma<true, true><<<gemm_grid, 256, 0, stream>>>(
        mean_bf, x_bf, Wt1, b1, nullptr, h_bf);

    // ---- layer 2 ----
    gather_bf16<<<gather_grid, 256, 0, stream>>>(h_bf, row_off, csr_src, mean_bf);
    sage_gemm_mfma<false, false><<<gemm_grid, 256, 0, stream>>>(
        mean_bf, h_bf, Wt2, b2, out, nullptr);
}

// Round 7
// 222.022 us; speedup vs baseline: 1.7780x; 1.0153x over previous
//
#include <hip/hip_runtime.h>

#define N_NODES 50000
#define N_EDGES 640000
#define D 128

#define SCAN_BLOCK 256
#define SCAN_NBLK ((N_NODES + SCAN_BLOCK - 1) / SCAN_BLOCK)  // 196

typedef __attribute__((ext_vector_type(8))) short bf16x8;   // 8 bf16 (4 VGPRs)
typedef __attribute__((ext_vector_type(4))) float f32x4;

__device__ __forceinline__ unsigned short f2bf(float f) {
    union { float f; unsigned u; } v; v.f = f;
    unsigned u = v.u;
    unsigned r = u + 0x7FFFu + ((u >> 16) & 1u);   // RNE
    return (unsigned short)(r >> 16);
}
__device__ __forceinline__ float bf2f(unsigned short s) {
    union { unsigned u; float f; } v; v.u = ((unsigned)s) << 16; return v.f;
}

// ---------------------------------------------------------------------------
// Zero an int buffer (replaces runtime fillBuffer: that was 41us for 200KB)
// ---------------------------------------------------------------------------
__global__ void zero_kernel(int* __restrict__ p, int n) {
    int i = blockIdx.x * blockDim.x + threadIdx.x;
    if (i < n) p[i] = 0;
}

// ---------------------------------------------------------------------------
// Degree histogram: deg[dst]++ per edge (int atomics, one-time)
// ---------------------------------------------------------------------------
__global__ void deg_kernel(const int* __restrict__ dst, int* __restrict__ deg) {
    int e = blockIdx.x * blockDim.x + threadIdx.x;
    if (e < N_EDGES) atomicAdd(&deg[dst[e]], 1);
}

// ---------------------------------------------------------------------------
// Hierarchical scan (3 kernels)
// ---------------------------------------------------------------------------
__global__ __launch_bounds__(SCAN_BLOCK) void scan_partial(const int* __restrict__ deg,
                                                           int* __restrict__ partial) {
    __shared__ int sm[SCAN_BLOCK];
    const int t = threadIdx.x;
    const int i = blockIdx.x * SCAN_BLOCK + t;
    sm[t] = (i < N_NODES) ? deg[i] : 0;
    __syncthreads();
#pragma unroll
    for (int off = SCAN_BLOCK / 2; off > 0; off >>= 1) {
        if (t < off) sm[t] += sm[t + off];
        __syncthreads();
    }
    if (t == 0) partial[blockIdx.x] = sm[0];
}

__global__ __launch_bounds__(SCAN_BLOCK) void scan_offsets(const int* __restrict__ partial,
                                                           int* __restrict__ block_off,
                                                           int* __restrict__ row_off) {
    __shared__ int sm[SCAN_BLOCK];
    const int t = threadIdx.x;
    int v = (t < SCAN_NBLK) ? partial[t] : 0;
    sm[t] = v;
    __syncthreads();
    int x = v;
#pragma unroll
    for (int off = 1; off < SCAN_BLOCK; off <<= 1) {
        int y = (t >= off) ? sm[t - off] : 0;
        __syncthreads();
        x += y;
        sm[t] = x;
        __syncthreads();
    }
    if (t < SCAN_NBLK) block_off[t] = x - v;
    if (t == SCAN_BLOCK - 1) row_off[N_NODES] = x;
}

__global__ __launch_bounds__(SCAN_BLOCK) void scan_final(const int* __restrict__ deg,
                                                         const int* __restrict__ block_off,
                                                         int* __restrict__ row_off,
                                                         int* __restrict__ cursor) {
    __shared__ int sm[SCAN_BLOCK];
    const int t = threadIdx.x;
    const int i = blockIdx.x * SCAN_BLOCK + t;
    int v = (i < N_NODES) ? deg[i] : 0;
    sm[t] = v;
    __syncthreads();
    int x = v;
#pragma unroll
    for (int off = 1; off < SCAN_BLOCK; off <<= 1) {
        int y = (t >= off) ? sm[t - off] : 0;
        __syncthreads();
        x += y;
        sm[t] = x;
        __syncthreads();
    }
    int excl = x - v + block_off[blockIdx.x];
    if (i < N_NODES) {
        row_off[i] = excl;
        cursor[i] = excl;
    }
}

// ---------------------------------------------------------------------------
// CSR fill: csr_src[cursor[dst[e]]++] = src[e]
// ---------------------------------------------------------------------------
__global__ void fill_csr(const int* __restrict__ src, const int* __restrict__ dst,
                         int* __restrict__ cursor, int* __restrict__ csr_src) {
    int e = blockIdx.x * blockDim.x + threadIdx.x;
    if (e < N_EDGES) {
        int pos = atomicAdd(&cursor[dst[e]], 1);
        csr_src[pos] = src[e];
    }
}

// ---------------------------------------------------------------------------
// fp32 -> bf16 elementwise (8 per thread)
// ---------------------------------------------------------------------------
__global__ void cvt_f32_bf16(const float* __restrict__ in,
                             unsigned short* __restrict__ outp, int n8) {
    int i = blockIdx.x * blockDim.x + threadIdx.x;
    if (i >= n8) return;
    float4 a = *reinterpret_cast<const float4*>(&in[(size_t)i * 8]);
    float4 b = *reinterpret_cast<const float4*>(&in[(size_t)i * 8 + 4]);
    bf16x8 o;
    o[0] = (short)f2bf(a.x); o[1] = (short)f2bf(a.y);
    o[2] = (short)f2bf(a.z); o[3] = (short)f2bf(a.w);
    o[4] = (short)f2bf(b.x); o[5] = (short)f2bf(b.y);
    o[6] = (short)f2bf(b.z); o[7] = (short)f2bf(b.w);
    *reinterpret_cast<bf16x8*>(&outp[(size_t)i * 8]) = o;
}

// ---------------------------------------------------------------------------
// Build Wt[col][k] bf16 from Wl[k][c], Wr[k][c] (k stacked to 256)
// ---------------------------------------------------------------------------
__global__ void build_wt(const float* __restrict__ Wl, const float* __restrict__ Wr,
                         unsigned short* __restrict__ Wt) {
    int i = blockIdx.x * blockDim.x + threadIdx.x;   // 128*256
    if (i >= 128 * 256) return;
    int c = i >> 8, k = i & 255;
    float v = (k < 128) ? Wl[k * 128 + c] : Wr[(k - 128) * 128 + c];
    Wt[c * 256 + k] = f2bf(v);
}

// ---------------------------------------------------------------------------
// Gather-aggregate (bf16 in/out, fp32 accumulate): one wave per node.
// Lane layout: grp = l>>4 walks neighbors (4 at a time, 2-way unrolled for
// MLP), (l&15)*8 = col slice. Shuffle-reduce across the 4 groups.
// ---------------------------------------------------------------------------
__global__ __launch_bounds__(256) void gather_bf16(const unsigned short* __restrict__ feat,
                                                   const int* __restrict__ row_off,
                                                   const int* __restrict__ csr_src,
                                                   unsigned short* __restrict__ mean) {
    int node = (blockIdx.x * 256 + threadIdx.x) >> 6;   // wave-uniform
    int l = threadIdx.x & 63;
    int grp = l >> 4;
    int c8 = (l & 15) * 8;
    int beg = row_off[node];
    int end = row_off[node + 1];

    float s0[8] = {}, s1[8] = {};
    int k = beg + grp;
    // 2-way unrolled: both row loads issued before either accumulate
    for (; k + 4 < end; k += 8) {
        int a0 = csr_src[k];
        int a1 = csr_src[k + 4];
        bf16x8 v0 = *reinterpret_cast<const bf16x8*>(&feat[(size_t)a0 * D + c8]);
        bf16x8 v1 = *reinterpret_cast<const bf16x8*>(&feat[(size_t)a1 * D + c8]);
#pragma unroll
        for (int j = 0; j < 8; ++j) s0[j] += bf2f((unsigned short)v0[j]);
#pragma unroll
        for (int j = 0; j < 8; ++j) s1[j] += bf2f((unsigned short)v1[j]);
    }
    if (k < end) {
        int a0 = csr_src[k];
        bf16x8 v0 = *reinterpret_cast<const bf16x8*>(&feat[(size_t)a0 * D + c8]);
#pragma unroll
        for (int j = 0; j < 8; ++j) s0[j] += bf2f((unsigned short)v0[j]);
    }
#pragma unroll
    for (int j = 0; j < 8; ++j) {
        float s = s0[j] + s1[j];
        s += __shfl_xor(s, 16, 64);
        s += __shfl_xor(s, 32, 64);
        s0[j] = s;
    }
    if (grp == 0) {
        float inv = 1.0f / fmaxf((float)(end - beg), 1.0f);
        bf16x8 o;
#pragma unroll
        for (int j = 0; j < 8; ++j) o[j] = (short)f2bf(s0[j] * inv);
        *reinterpret_cast<bf16x8*>(&mean[(size_t)node * D + c8]) = o;
    }
}

// ---------------------------------------------------------------------------
// MFMA GEMM: out = [relu]( [mean|root] @ [Wl;Wr] + bias ), K=256, bf16 inputs.
// 4 waves/block, BM=64; wave = 16 rows x 128 cols = 8 accum frags, 64 MFMAs.
// A-frag: row=l&15, k=(l>>4)*8+j. B-frag from Wt[col][k]: col=l&15.
// C/D: col=l&15, row=(l>>4)*4+reg (verified layout).
// No LDS: Wt (64KB) is L1/L2-resident; A rows read once.
// ---------------------------------------------------------------------------
template <bool RELU, bool OUTBF16>
__global__ __launch_bounds__(256) void sage_gemm_mfma(
    const unsigned short* __restrict__ Amean,   // [N,128] bf16
    const unsigned short* __restrict__ Aroot,   // [N,128] bf16
    const unsigned short* __restrict__ Wt,      // [128 cols][256 k] bf16
    const float* __restrict__ bias,             // [128] fp32
    float* __restrict__ outf,                   // fp32 out (if !OUTBF16)
    unsigned short* __restrict__ outb)          // bf16 out (if OUTBF16)
{
    const int t = threadIdx.x;
    const int w = t >> 6;
    const int l = t & 63;
    const int row0 = blockIdx.x * 64 + w * 16;

    int arow = row0 + (l & 15);
    if (arow >= N_NODES) arow = N_NODES - 1;    // clamp; C-write guarded
    const int k8 = (l >> 4) * 8;

    f32x4 acc[8] = {};

#pragma unroll
    for (int kc = 0; kc < 8; ++kc) {
        const unsigned short* ap = (kc < 4)
            ? &Amean[(size_t)arow * D + kc * 32 + k8]
            : &Aroot[(size_t)arow * D + (kc - 4) * 32 + k8];
        bf16x8 af = *reinterpret_cast<const bf16x8*>(ap);
#pragma unroll
        for (int c = 0; c < 8; ++c) {
            bf16x8 bf = *reinterpret_cast<const bf16x8*>(
                &Wt[(size_t)(c * 16 + (l & 15)) * 256 + kc * 32 + k8]);
            acc[c] = __builtin_amdgcn_mfma_f32_16x16x32_bf16(af, bf, acc[c], 0, 0, 0);
        }
    }

    const int rbase = row0 + (l >> 4) * 4;
#pragma unroll
    for (int c = 0; c < 8; ++c) {
        const int col = c * 16 + (l & 15);
        const float b = bias[col];
#pragma unroll
        for (int i = 0; i < 4; ++i) {
            int r = rbase + i;
            if (r < N_NODES) {
                float v = acc[c][i] + b;
                if (RELU) v = fmaxf(v, 0.f);
                if (OUTBF16) outb[(size_t)r * D + col] = f2bf(v);
                else         outf[(size_t)r * D + col] = v;
            }
        }
    }
}

// ---------------------------------------------------------------------------
extern "C" void kernel_launch(void* const* d_in, const int* in_sizes, int n_in,
                              void* d_out, int out_size, void* d_ws, size_t ws_size,
                              hipStream_t stream) {
    const float* x   = (const float*)d_in[0];
    const int*   ei  = (const int*)d_in[1];
    const float* W1l = (const float*)d_in[2];
    const float* b1  = (const float*)d_in[3];
    const float* W1r = (const float*)d_in[4];
    const float* W2l = (const float*)d_in[5];
    const float* b2  = (const float*)d_in[6];
    const float* W2r = (const float*)d_in[7];
    float* out = (float*)d_out;

    const int* src = ei;             // edge_index[0]
    const int* dst = ei + N_EDGES;   // edge_index[1]

    // Workspace layout (ints first, then bf16 arrays; all 16B aligned)
    int* deg       = (int*)d_ws;                     // 51200
    int* row_off   = deg + 51200;                    // 51200 (N+1 used)
    int* cursor    = row_off + 51200;                // 51200
    int* partial   = cursor + 51200;                 // 256
    int* block_off = partial + 256;                  // 256
    int* csr_src   = block_off + 256;                // 640000
    unsigned short* x_bf    = (unsigned short*)(csr_src + N_EDGES);  // N*D
    unsigned short* h_bf    = x_bf + (size_t)N_NODES * D;            // N*D
    unsigned short* mean_bf = h_bf + (size_t)N_NODES * D;            // N*D
    unsigned short* Wt1     = mean_bf + (size_t)N_NODES * D;         // 128*256
    unsigned short* Wt2     = Wt1 + 128 * 256;                       // 128*256

    // ---- one-time CSR build + conversions ----
    zero_kernel<<<(N_NODES + 255) / 256, 256, 0, stream>>>(deg, N_NODES);
    deg_kernel<<<(N_EDGES + 255) / 256, 256, 0, stream>>>(dst, deg);
    scan_partial<<<SCAN_NBLK, SCAN_BLOCK, 0, stream>>>(deg, partial);
    scan_offsets<<<1, SCAN_BLOCK, 0, stream>>>(partial, block_off, row_off);
    scan_final<<<SCAN_NBLK, SCAN_BLOCK, 0, stream>>>(deg, block_off, row_off, cursor);
    fill_csr<<<(N_EDGES + 255) / 256, 256, 0, stream>>>(src, dst, cursor, csr_src);

    cvt_f32_bf16<<<(N_NODES * D / 8 + 255) / 256, 256, 0, stream>>>(x, x_bf, N_NODES * D / 8);
    build_wt<<<128, 256, 0, stream>>>(W1l, W1r, Wt1);
    build_wt<<<128, 256, 0, stream>>>(W2l, W2r, Wt2);

    const int gather_grid = N_NODES * 64 / 256;     // 12500
    const int gemm_grid = (N_NODES + 63) / 64;      // 782

    // ---- layer 1 ----
    gather_bf16<<<gather_grid, 256, 0, stream>>>(x_bf, row_off, csr_src, mean_bf);
    sage_gemm_mfma<true, true><<<gemm_grid, 256, 0, stream>>>(
        mean_bf, x_bf, Wt1, b1, nullptr, h_bf);

    // ---- layer 2 ----
    gather_bf16<<<gather_grid, 256, 0, stream>>>(h_bf, row_off, csr_src, mean_bf);
    sage_gemm_mfma<false, false><<<gemm_grid, 256, 0, stream>>>(
        mean_bf, h_bf, Wt2, b2, out, nullptr);
}

// Round 8
// 169.264 us; speedup vs baseline: 2.3321x; 1.3117x over previous
//
#include <hip/hip_runtime.h>

#define N_NODES 50000
#define N_EDGES 640000
#define D 128

#define SCAN_BLOCK 256
#define SCAN_NBLK ((N_NODES + SCAN_BLOCK - 1) / SCAN_BLOCK)  // 196

typedef __attribute__((ext_vector_type(8))) short bf16x8;   // 8 bf16 (4 VGPRs)
typedef __attribute__((ext_vector_type(4))) float f32x4;

__device__ __forceinline__ unsigned short f2bf(float f) {
    union { float f; unsigned u; } v; v.f = f;
    unsigned u = v.u;
    unsigned r = u + 0x7FFFu + ((u >> 16) & 1u);   // RNE
    return (unsigned short)(r >> 16);
}
__device__ __forceinline__ float bf2f(unsigned short s) {
    union { unsigned u; float f; } v; v.u = ((unsigned)s) << 16; return v.f;
}

// ---------------------------------------------------------------------------
// Zero an int buffer (runtime fillBuffer was 41us for 200KB)
// ---------------------------------------------------------------------------
__global__ void zero_kernel(int* __restrict__ p, int n) {
    int i = blockIdx.x * blockDim.x + threadIdx.x;
    if (i < n) p[i] = 0;
}

// ---------------------------------------------------------------------------
// Degree histogram: deg[dst]++ per edge (int atomics, one-time)
// ---------------------------------------------------------------------------
__global__ void deg_kernel(const int* __restrict__ dst, int* __restrict__ deg) {
    int e = blockIdx.x * blockDim.x + threadIdx.x;
    if (e < N_EDGES) atomicAdd(&deg[dst[e]], 1);
}

// ---------------------------------------------------------------------------
// Hierarchical scan (3 kernels)
// ---------------------------------------------------------------------------
__global__ __launch_bounds__(SCAN_BLOCK) void scan_partial(const int* __restrict__ deg,
                                                           int* __restrict__ partial) {
    __shared__ int sm[SCAN_BLOCK];
    const int t = threadIdx.x;
    const int i = blockIdx.x * SCAN_BLOCK + t;
    sm[t] = (i < N_NODES) ? deg[i] : 0;
    __syncthreads();
#pragma unroll
    for (int off = SCAN_BLOCK / 2; off > 0; off >>= 1) {
        if (t < off) sm[t] += sm[t + off];
        __syncthreads();
    }
    if (t == 0) partial[blockIdx.x] = sm[0];
}

__global__ __launch_bounds__(SCAN_BLOCK) void scan_offsets(const int* __restrict__ partial,
                                                           int* __restrict__ block_off,
                                                           int* __restrict__ row_off) {
    __shared__ int sm[SCAN_BLOCK];
    const int t = threadIdx.x;
    int v = (t < SCAN_NBLK) ? partial[t] : 0;
    sm[t] = v;
    __syncthreads();
    int x = v;
#pragma unroll
    for (int off = 1; off < SCAN_BLOCK; off <<= 1) {
        int y = (t >= off) ? sm[t - off] : 0;
        __syncthreads();
        x += y;
        sm[t] = x;
        __syncthreads();
    }
    if (t < SCAN_NBLK) block_off[t] = x - v;
    if (t == SCAN_BLOCK - 1) row_off[N_NODES] = x;
}

__global__ __launch_bounds__(SCAN_BLOCK) void scan_final(const int* __restrict__ deg,
                                                         const int* __restrict__ block_off,
                                                         int* __restrict__ row_off,
                                                         int* __restrict__ cursor) {
    __shared__ int sm[SCAN_BLOCK];
    const int t = threadIdx.x;
    const int i = blockIdx.x * SCAN_BLOCK + t;
    int v = (i < N_NODES) ? deg[i] : 0;
    sm[t] = v;
    __syncthreads();
    int x = v;
#pragma unroll
    for (int off = 1; off < SCAN_BLOCK; off <<= 1) {
        int y = (t >= off) ? sm[t - off] : 0;
        __syncthreads();
        x += y;
        sm[t] = x;
        __syncthreads();
    }
    int excl = x - v + block_off[blockIdx.x];
    if (i < N_NODES) {
        row_off[i] = excl;
        cursor[i] = excl;
    }
}

// ---------------------------------------------------------------------------
// CSR fill: csr_src[cursor[dst[e]]++] = src[e]
// ---------------------------------------------------------------------------
__global__ void fill_csr(const int* __restrict__ src, const int* __restrict__ dst,
                         int* __restrict__ cursor, int* __restrict__ csr_src) {
    int e = blockIdx.x * blockDim.x + threadIdx.x;
    if (e < N_EDGES) {
        int pos = atomicAdd(&cursor[dst[e]], 1);
        csr_src[pos] = src[e];
    }
}

// ---------------------------------------------------------------------------
// fp32 -> bf16 elementwise (8 per thread)
// ---------------------------------------------------------------------------
__global__ void cvt_f32_bf16(const float* __restrict__ in,
                             unsigned short* __restrict__ outp, int n8) {
    int i = blockIdx.x * blockDim.x + threadIdx.x;
    if (i >= n8) return;
    float4 a = *reinterpret_cast<const float4*>(&in[(size_t)i * 8]);
    float4 b = *reinterpret_cast<const float4*>(&in[(size_t)i * 8 + 4]);
    bf16x8 o;
    o[0] = (short)f2bf(a.x); o[1] = (short)f2bf(a.y);
    o[2] = (short)f2bf(a.z); o[3] = (short)f2bf(a.w);
    o[4] = (short)f2bf(b.x); o[5] = (short)f2bf(b.y);
    o[6] = (short)f2bf(b.z); o[7] = (short)f2bf(b.w);
    *reinterpret_cast<bf16x8*>(&outp[(size_t)i * 8]) = o;
}

// ---------------------------------------------------------------------------
// Build Wt[col][k] bf16 from Wl[k][c], Wr[k][c] (k stacked to 256)
// ---------------------------------------------------------------------------
__global__ void build_wt(const float* __restrict__ Wl, const float* __restrict__ Wr,
                         unsigned short* __restrict__ Wt) {
    int i = blockIdx.x * blockDim.x + threadIdx.x;   // 128*256
    if (i >= 128 * 256) return;
    int c = i >> 8, k = i & 255;
    float v = (k < 128) ? Wl[k * 128 + c] : Wr[(k - 128) * 128 + c];
    Wt[c * 256 + k] = f2bf(v);
}

// ---------------------------------------------------------------------------
// Gather-aggregate (bf16 in/out, fp32 accumulate): one wave per node.
// ---------------------------------------------------------------------------
__global__ __launch_bounds__(256) void gather_bf16(const unsigned short* __restrict__ feat,
                                                   const int* __restrict__ row_off,
                                                   const int* __restrict__ csr_src,
                                                   unsigned short* __restrict__ mean) {
    int node = (blockIdx.x * 256 + threadIdx.x) >> 6;   // wave-uniform
    int l = threadIdx.x & 63;
    int grp = l >> 4;
    int c8 = (l & 15) * 8;
    int beg = row_off[node];
    int end = row_off[node + 1];

    float s0[8] = {}, s1[8] = {};
    int k = beg + grp;
    for (; k + 4 < end; k += 8) {
        int a0 = csr_src[k];
        int a1 = csr_src[k + 4];
        bf16x8 v0 = *reinterpret_cast<const bf16x8*>(&feat[(size_t)a0 * D + c8]);
        bf16x8 v1 = *reinterpret_cast<const bf16x8*>(&feat[(size_t)a1 * D + c8]);
#pragma unroll
        for (int j = 0; j < 8; ++j) s0[j] += bf2f((unsigned short)v0[j]);
#pragma unroll
        for (int j = 0; j < 8; ++j) s1[j] += bf2f((unsigned short)v1[j]);
    }
    if (k < end) {
        int a0 = csr_src[k];
        bf16x8 v0 = *reinterpret_cast<const bf16x8*>(&feat[(size_t)a0 * D + c8]);
#pragma unroll
        for (int j = 0; j < 8; ++j) s0[j] += bf2f((unsigned short)v0[j]);
    }
#pragma unroll
    for (int j = 0; j < 8; ++j) {
        float s = s0[j] + s1[j];
        s += __shfl_xor(s, 16, 64);
        s += __shfl_xor(s, 32, 64);
        s0[j] = s;
    }
    if (grp == 0) {
        float inv = 1.0f / fmaxf((float)(end - beg), 1.0f);
        bf16x8 o;
#pragma unroll
        for (int j = 0; j < 8; ++j) o[j] = (short)f2bf(s0[j] * inv);
        *reinterpret_cast<bf16x8*>(&mean[(size_t)node * D + c8]) = o;
    }
}

// ---------------------------------------------------------------------------
// MFMA GEMM with LDS-staged W: out = [relu]( [mean|root] @ [Wl;Wr] + bias ).
// 512 thr / 8 waves, BM=128 rows (16/wave). Whole Wt (K=256 x 128 cols, 64KB)
// staged in LDS as 16B entries: entry(col,chunk) = col*32 + (chunk^(col&7)),
// chunk = k/8 (0..31). XOR swizzle spreads both staging writes and frag reads
// evenly over the 8 16B-bank-slots (conflict-free). A-frags hoisted to regs
// before staging so HBM latency hides under the staging phase.
// ---------------------------------------------------------------------------
template <bool RELU, bool OUTBF16>
__global__ __launch_bounds__(512) void sage_gemm_mfma(
    const unsigned short* __restrict__ Amean,   // [N,128] bf16
    const unsigned short* __restrict__ Aroot,   // [N,128] bf16
    const unsigned short* __restrict__ Wt,      // [128 cols][256 k] bf16
    const float* __restrict__ bias,             // [128] fp32
    float* __restrict__ outf,                   // fp32 out (if !OUTBF16)
    unsigned short* __restrict__ outb)          // bf16 out (if OUTBF16)
{
    __shared__ bf16x8 ws[4096];                 // 64KB: swizzled Wt
    const int t = threadIdx.x;
    const int w = t >> 6;
    const int l = t & 63;
    const int row0 = blockIdx.x * 128 + w * 16;

    int arow = row0 + (l & 15);
    if (arow >= N_NODES) arow = N_NODES - 1;    // clamp; C-write guarded
    const int k8 = (l >> 4) * 8;

    // hoist all 8 A-frags (issued before staging; latency overlapped)
    bf16x8 a[8];
#pragma unroll
    for (int kc = 0; kc < 8; ++kc) {
        const unsigned short* ap = (kc < 4)
            ? &Amean[(size_t)arow * D + kc * 32 + k8]
            : &Aroot[(size_t)arow * D + (kc - 4) * 32 + k8];
        a[kc] = *reinterpret_cast<const bf16x8*>(ap);
    }

    // stage Wt -> LDS (coalesced global, swizzled conflict-free LDS writes)
#pragma unroll
    for (int i = 0; i < 8; ++i) {
        int g = i * 512 + t;                    // 16B chunk index in Wt
        int col = g >> 5;
        int chunk = g & 31;
        ws[col * 32 + (chunk ^ (col & 7))] =
            *reinterpret_cast<const bf16x8*>(&Wt[(size_t)g * 8]);
    }
    __syncthreads();

    f32x4 acc[8] = {};
    const int l15 = l & 15;
    const int kg = l >> 4;
    const int swz = l & 7;
#pragma unroll
    for (int kc = 0; kc < 8; ++kc) {
#pragma unroll
        for (int c = 0; c < 8; ++c) {
            bf16x8 bfr = ws[c * 512 + l15 * 32 + ((kc * 4 + kg) ^ swz)];
            acc[c] = __builtin_amdgcn_mfma_f32_16x16x32_bf16(a[kc], bfr, acc[c], 0, 0, 0);
        }
    }

    const int rbase = row0 + kg * 4;
#pragma unroll
    for (int c = 0; c < 8; ++c) {
        const int col = c * 16 + l15;
        const float b = bias[col];
#pragma unroll
        for (int i = 0; i < 4; ++i) {
            int r = rbase + i;
            if (r < N_NODES) {
                float v = acc[c][i] + b;
                if (RELU) v = fmaxf(v, 0.f);
                if (OUTBF16) outb[(size_t)r * D + col] = f2bf(v);
                else         outf[(size_t)r * D + col] = v;
            }
        }
    }
}

// ---------------------------------------------------------------------------
extern "C" void kernel_launch(void* const* d_in, const int* in_sizes, int n_in,
                              void* d_out, int out_size, void* d_ws, size_t ws_size,
                              hipStream_t stream) {
    const float* x   = (const float*)d_in[0];
    const int*   ei  = (const int*)d_in[1];
    const float* W1l = (const float*)d_in[2];
    const float* b1  = (const float*)d_in[3];
    const float* W1r = (const float*)d_in[4];
    const float* W2l = (const float*)d_in[5];
    const float* b2  = (const float*)d_in[6];
    const float* W2r = (const float*)d_in[7];
    float* out = (float*)d_out;

    const int* src = ei;             // edge_index[0]
    const int* dst = ei + N_EDGES;   // edge_index[1]

    // Workspace layout (ints first, then bf16 arrays; all 16B aligned)
    int* deg       = (int*)d_ws;                     // 51200
    int* row_off   = deg + 51200;                    // 51200 (N+1 used)
    int* cursor    = row_off + 51200;                // 51200
    int* partial   = cursor + 51200;                 // 256
    int* block_off = partial + 256;                  // 256
    int* csr_src   = block_off + 256;                // 640000
    unsigned short* x_bf    = (unsigned short*)(csr_src + N_EDGES);  // N*D
    unsigned short* h_bf    = x_bf + (size_t)N_NODES * D;            // N*D
    unsigned short* mean_bf = h_bf + (size_t)N_NODES * D;            // N*D
    unsigned short* Wt1     = mean_bf + (size_t)N_NODES * D;         // 128*256
    unsigned short* Wt2     = Wt1 + 128 * 256;                       // 128*256

    // ---- one-time CSR build + conversions ----
    zero_kernel<<<(N_NODES + 255) / 256, 256, 0, stream>>>(deg, N_NODES);
    deg_kernel<<<(N_EDGES + 255) / 256, 256, 0, stream>>>(dst, deg);
    scan_partial<<<SCAN_NBLK, SCAN_BLOCK, 0, stream>>>(deg, partial);
    scan_offsets<<<1, SCAN_BLOCK, 0, stream>>>(partial, block_off, row_off);
    scan_final<<<SCAN_NBLK, SCAN_BLOCK, 0, stream>>>(deg, block_off, row_off, cursor);
    fill_csr<<<(N_EDGES + 255) / 256, 256, 0, stream>>>(src, dst, cursor, csr_src);

    cvt_f32_bf16<<<(N_NODES * D / 8 + 255) / 256, 256, 0, stream>>>(x, x_bf, N_NODES * D / 8);
    build_wt<<<128, 256, 0, stream>>>(W1l, W1r, Wt1);
    build_wt<<<128, 256, 0, stream>>>(W2l, W2r, Wt2);

    const int gather_grid = N_NODES * 64 / 256;       // 12500
    const int gemm_grid = (N_NODES + 127) / 128;      // 391

    // ---- layer 1 ----
    gather_bf16<<<gather_grid, 256, 0, stream>>>(x_bf, row_off, csr_src, mean_bf);
    sage_gemm_mfma<true, true><<<gemm_grid, 512, 0, stream>>>(
        mean_bf, x_bf, Wt1, b1, nullptr, h_bf);

    // ---- layer 2 ----
    gather_bf16<<<gather_grid, 256, 0, stream>>>(h_bf, row_off, csr_src, mean_bf);
    sage_gemm_mfma<false, false><<<gemm_grid, 512, 0, stream>>>(
        mean_bf, h_bf, Wt2, b2, out, nullptr);
}

// Round 9
// 158.243 us; speedup vs baseline: 2.4946x; 1.0696x over previous
//
#include <hip/hip_runtime.h>

#define N_NODES 50000
#define N_EDGES 640000
#define D 128

#define SCAN_BLOCK 256
#define SCAN_NBLK ((N_NODES + SCAN_BLOCK - 1) / SCAN_BLOCK)  // 196

typedef __attribute__((ext_vector_type(8))) short bf16x8;   // 8 bf16 (4 VGPRs)
typedef __attribute__((ext_vector_type(4))) float f32x4;

__device__ __forceinline__ unsigned short f2bf(float f) {
    union { float f; unsigned u; } v; v.f = f;
    unsigned u = v.u;
    unsigned r = u + 0x7FFFu + ((u >> 16) & 1u);   // RNE
    return (unsigned short)(r >> 16);
}
__device__ __forceinline__ float bf2f(unsigned short s) {
    union { unsigned u; float f; } v; v.u = ((unsigned)s) << 16; return v.f;
}

// ---------------------------------------------------------------------------
// Zero an int buffer
// ---------------------------------------------------------------------------
__global__ void zero_kernel(int* __restrict__ p, int n) {
    int i = blockIdx.x * blockDim.x + threadIdx.x;
    if (i < n) p[i] = 0;
}

// ---------------------------------------------------------------------------
// Degree histogram: deg[dst]++ per edge (int atomics, one-time)
// ---------------------------------------------------------------------------
__global__ void deg_kernel(const int* __restrict__ dst, int* __restrict__ deg) {
    int e = blockIdx.x * blockDim.x + threadIdx.x;
    if (e < N_EDGES) atomicAdd(&deg[dst[e]], 1);
}

// ---------------------------------------------------------------------------
// Hierarchical scan (3 kernels)
// ---------------------------------------------------------------------------
__global__ __launch_bounds__(SCAN_BLOCK) void scan_partial(const int* __restrict__ deg,
                                                           int* __restrict__ partial) {
    __shared__ int sm[SCAN_BLOCK];
    const int t = threadIdx.x;
    const int i = blockIdx.x * SCAN_BLOCK + t;
    sm[t] = (i < N_NODES) ? deg[i] : 0;
    __syncthreads();
#pragma unroll
    for (int off = SCAN_BLOCK / 2; off > 0; off >>= 1) {
        if (t < off) sm[t] += sm[t + off];
        __syncthreads();
    }
    if (t == 0) partial[blockIdx.x] = sm[0];
}

__global__ __launch_bounds__(SCAN_BLOCK) void scan_offsets(const int* __restrict__ partial,
                                                           int* __restrict__ block_off,
                                                           int* __restrict__ row_off) {
    __shared__ int sm[SCAN_BLOCK];
    const int t = threadIdx.x;
    int v = (t < SCAN_NBLK) ? partial[t] : 0;
    sm[t] = v;
    __syncthreads();
    int x = v;
#pragma unroll
    for (int off = 1; off < SCAN_BLOCK; off <<= 1) {
        int y = (t >= off) ? sm[t - off] : 0;
        __syncthreads();
        x += y;
        sm[t] = x;
        __syncthreads();
    }
    if (t < SCAN_NBLK) block_off[t] = x - v;
    if (t == SCAN_BLOCK - 1) row_off[N_NODES] = x;
}

__global__ __launch_bounds__(SCAN_BLOCK) void scan_final(const int* __restrict__ deg,
                                                         const int* __restrict__ block_off,
                                                         int* __restrict__ row_off,
                                                         int* __restrict__ cursor) {
    __shared__ int sm[SCAN_BLOCK];
    const int t = threadIdx.x;
    const int i = blockIdx.x * SCAN_BLOCK + t;
    int v = (i < N_NODES) ? deg[i] : 0;
    sm[t] = v;
    __syncthreads();
    int x = v;
#pragma unroll
    for (int off = 1; off < SCAN_BLOCK; off <<= 1) {
        int y = (t >= off) ? sm[t - off] : 0;
        __syncthreads();
        x += y;
        sm[t] = x;
        __syncthreads();
    }
    int excl = x - v + block_off[blockIdx.x];
    if (i < N_NODES) {
        row_off[i] = excl;
        cursor[i] = excl;
    }
}

// ---------------------------------------------------------------------------
// CSR fill: csr_src[cursor[dst[e]]++] = src[e]
// ---------------------------------------------------------------------------
__global__ void fill_csr(const int* __restrict__ src, const int* __restrict__ dst,
                         int* __restrict__ cursor, int* __restrict__ csr_src) {
    int e = blockIdx.x * blockDim.x + threadIdx.x;
    if (e < N_EDGES) {
        int pos = atomicAdd(&cursor[dst[e]], 1);
        csr_src[pos] = src[e];
    }
}

// ---------------------------------------------------------------------------
// Fused conversions: blocks [0,3125) cvt x->bf16; [3125,3253) Wt1; [3253,3381) Wt2
// ---------------------------------------------------------------------------
__global__ void cvt_and_wt(const float* __restrict__ x,
                           const float* __restrict__ W1l, const float* __restrict__ W1r,
                           const float* __restrict__ W2l, const float* __restrict__ W2r,
                           unsigned short* __restrict__ x_bf,
                           unsigned short* __restrict__ Wt1,
                           unsigned short* __restrict__ Wt2) {
    const int b = blockIdx.x;
    const int t = threadIdx.x;
    if (b < 3125) {                     // 3125*256*8 = 6.4M = N_NODES*D exactly
        int i = b * 256 + t;
        float4 a = *reinterpret_cast<const float4*>(&x[(size_t)i * 8]);
        float4 c = *reinterpret_cast<const float4*>(&x[(size_t)i * 8 + 4]);
        bf16x8 o;
        o[0] = (short)f2bf(a.x); o[1] = (short)f2bf(a.y);
        o[2] = (short)f2bf(a.z); o[3] = (short)f2bf(a.w);
        o[4] = (short)f2bf(c.x); o[5] = (short)f2bf(c.y);
        o[6] = (short)f2bf(c.z); o[7] = (short)f2bf(c.w);
        *reinterpret_cast<bf16x8*>(&x_bf[(size_t)i * 8]) = o;
    } else {
        const bool second = (b >= 3125 + 128);
        const float* Wl = second ? W2l : W1l;
        const float* Wr = second ? W2r : W1r;
        unsigned short* Wt = second ? Wt2 : Wt1;
        int i = (b - (second ? 3253 : 3125)) * 256 + t;   // 0..32767
        int c = i >> 8, k = i & 255;
        float v = (k < 128) ? Wl[k * 128 + c] : Wr[(k - 128) * 128 + c];
        Wt[c * 256 + k] = f2bf(v);
    }
}

// ---------------------------------------------------------------------------
// Gather-aggregate (bf16 in/out, fp32 accumulate): one wave per node.
// Group g (16 lanes) handles neighbors beg+g*4+{0..3}, stride 16 -> per trip
// 4 csr loads then 4 independent row loads (16 rows in flight per wave).
// Invalid slots load a safe duplicate row and accumulate with 0-multiplier.
// ---------------------------------------------------------------------------
__global__ __launch_bounds__(256) void gather_bf16(const unsigned short* __restrict__ feat,
                                                   const int* __restrict__ row_off,
                                                   const int* __restrict__ csr_src,
                                                   unsigned short* __restrict__ mean) {
    int node = (blockIdx.x * 256 + threadIdx.x) >> 6;   // wave-uniform
    int l = threadIdx.x & 63;
    int grp = l >> 4;
    int c8 = (l & 15) * 8;
    int beg = row_off[node];
    int end = row_off[node + 1];

    float s[8] = {};
    for (int kb = beg + grp * 4; kb < end; kb += 16) {
        int idx[4];
#pragma unroll
        for (int j = 0; j < 4; ++j) {
            int k = kb + j;
            idx[j] = csr_src[k < end ? k : end - 1];    // end-1 >= beg here
        }
        bf16x8 v[4];
#pragma unroll
        for (int j = 0; j < 4; ++j)
            v[j] = *reinterpret_cast<const bf16x8*>(&feat[(size_t)idx[j] * D + c8]);
#pragma unroll
        for (int j = 0; j < 4; ++j) {
            float m = (kb + j < end) ? 1.0f : 0.0f;
#pragma unroll
            for (int q = 0; q < 8; ++q) s[q] += m * bf2f((unsigned short)v[j][q]);
        }
    }
#pragma unroll
    for (int j = 0; j < 8; ++j) {
        float v = s[j];
        v += __shfl_xor(v, 16, 64);
        v += __shfl_xor(v, 32, 64);
        s[j] = v;
    }
    if (grp == 0) {
        float inv = 1.0f / fmaxf((float)(end - beg), 1.0f);
        bf16x8 o;
#pragma unroll
        for (int j = 0; j < 8; ++j) o[j] = (short)f2bf(s[j] * inv);
        *reinterpret_cast<bf16x8*>(&mean[(size_t)node * D + c8]) = o;
    }
}

// ---------------------------------------------------------------------------
// MFMA GEMM with LDS-staged W: out = [relu]( [mean|root] @ [Wl;Wr] + bias ).
// 512 thr / 8 waves, BM=128 rows (16/wave). Whole Wt (64KB) in LDS, XOR-
// swizzled 16B entries (conflict-free stage + frag reads). A-frags hoisted.
// ---------------------------------------------------------------------------
template <bool RELU, bool OUTBF16>
__global__ __launch_bounds__(512) void sage_gemm_mfma(
    const unsigned short* __restrict__ Amean,   // [N,128] bf16
    const unsigned short* __restrict__ Aroot,   // [N,128] bf16
    const unsigned short* __restrict__ Wt,      // [128 cols][256 k] bf16
    const float* __restrict__ bias,             // [128] fp32
    float* __restrict__ outf,                   // fp32 out (if !OUTBF16)
    unsigned short* __restrict__ outb)          // bf16 out (if OUTBF16)
{
    __shared__ bf16x8 ws[4096];                 // 64KB: swizzled Wt
    const int t = threadIdx.x;
    const int w = t >> 6;
    const int l = t & 63;
    const int row0 = blockIdx.x * 128 + w * 16;

    int arow = row0 + (l & 15);
    if (arow >= N_NODES) arow = N_NODES - 1;    // clamp; C-write guarded
    const int k8 = (l >> 4) * 8;

    bf16x8 a[8];
#pragma unroll
    for (int kc = 0; kc < 8; ++kc) {
        const unsigned short* ap = (kc < 4)
            ? &Amean[(size_t)arow * D + kc * 32 + k8]
            : &Aroot[(size_t)arow * D + (kc - 4) * 32 + k8];
        a[kc] = *reinterpret_cast<const bf16x8*>(ap);
    }

#pragma unroll
    for (int i = 0; i < 8; ++i) {
        int g = i * 512 + t;                    // 16B chunk index in Wt
        int col = g >> 5;
        int chunk = g & 31;
        ws[col * 32 + (chunk ^ (col & 7))] =
            *reinterpret_cast<const bf16x8*>(&Wt[(size_t)g * 8]);
    }
    __syncthreads();

    f32x4 acc[8] = {};
    const int l15 = l & 15;
    const int kg = l >> 4;
    const int swz = l & 7;
#pragma unroll
    for (int kc = 0; kc < 8; ++kc) {
#pragma unroll
        for (int c = 0; c < 8; ++c) {
            bf16x8 bfr = ws[c * 512 + l15 * 32 + ((kc * 4 + kg) ^ swz)];
            acc[c] = __builtin_amdgcn_mfma_f32_16x16x32_bf16(a[kc], bfr, acc[c], 0, 0, 0);
        }
    }

    const int rbase = row0 + kg * 4;
#pragma unroll
    for (int c = 0; c < 8; ++c) {
        const int col = c * 16 + l15;
        const float b = bias[col];
#pragma unroll
        for (int i = 0; i < 4; ++i) {
            int r = rbase + i;
            if (r < N_NODES) {
                float v = acc[c][i] + b;
                if (RELU) v = fmaxf(v, 0.f);
                if (OUTBF16) outb[(size_t)r * D + col] = f2bf(v);
                else         outf[(size_t)r * D + col] = v;
            }
        }
    }
}

// ---------------------------------------------------------------------------
extern "C" void kernel_launch(void* const* d_in, const int* in_sizes, int n_in,
                              void* d_out, int out_size, void* d_ws, size_t ws_size,
                              hipStream_t stream) {
    const float* x   = (const float*)d_in[0];
    const int*   ei  = (const int*)d_in[1];
    const float* W1l = (const float*)d_in[2];
    const float* b1  = (const float*)d_in[3];
    const float* W1r = (const float*)d_in[4];
    const float* W2l = (const float*)d_in[5];
    const float* b2  = (const float*)d_in[6];
    const float* W2r = (const float*)d_in[7];
    float* out = (float*)d_out;

    const int* src = ei;             // edge_index[0]
    const int* dst = ei + N_EDGES;   // edge_index[1]

    // Workspace layout (ints first, then bf16 arrays; all 16B aligned)
    int* deg       = (int*)d_ws;                     // 51200
    int* row_off   = deg + 51200;                    // 51200 (N+1 used)
    int* cursor    = row_off + 51200;                // 51200
    int* partial   = cursor + 51200;                 // 256
    int* block_off = partial + 256;                  // 256
    int* csr_src   = block_off + 256;                // 640000
    unsigned short* x_bf    = (unsigned short*)(csr_src + N_EDGES);  // N*D
    unsigned short* h_bf    = x_bf + (size_t)N_NODES * D;            // N*D
    unsigned short* mean_bf = h_bf + (size_t)N_NODES * D;            // N*D
    unsigned short* Wt1     = mean_bf + (size_t)N_NODES * D;         // 128*256
    unsigned short* Wt2     = Wt1 + 128 * 256;                       // 128*256

    // ---- one-time CSR build + conversions ----
    zero_kernel<<<(N_NODES + 255) / 256, 256, 0, stream>>>(deg, N_NODES);
    deg_kernel<<<(N_EDGES + 255) / 256, 256, 0, stream>>>(dst, deg);
    scan_partial<<<SCAN_NBLK, SCAN_BLOCK, 0, stream>>>(deg, partial);
    scan_offsets<<<1, SCAN_BLOCK, 0, stream>>>(partial, block_off, row_off);
    scan_final<<<SCAN_NBLK, SCAN_BLOCK, 0, stream>>>(deg, block_off, row_off, cursor);
    fill_csr<<<(N_EDGES + 255) / 256, 256, 0, stream>>>(src, dst, cursor, csr_src);

    cvt_and_wt<<<3125 + 256, 256, 0, stream>>>(x, W1l, W1r, W2l, W2r, x_bf, Wt1, Wt2);

    const int gather_grid = N_NODES * 64 / 256;       // 12500
    const int gemm_grid = (N_NODES + 127) / 128;      // 391

    // ---- layer 1 ----
    gather_bf16<<<gather_grid, 256, 0, stream>>>(x_bf, row_off, csr_src, mean_bf);
    sage_gemm_mfma<true, true><<<gemm_grid, 512, 0, stream>>>(
        mean_bf, x_bf, Wt1, b1, nullptr, h_bf);

    // ---- layer 2 ----
    gather_bf16<<<gather_grid, 256, 0, stream>>>(h_bf, row_off, csr_src, mean_bf);
    sage_gemm_mfma<false, false><<<gemm_grid, 512, 0, stream>>>(
        mean_bf, h_bf, Wt2, b2, out, nullptr);
}